// Round 10
// baseline (124.269 us; speedup 1.0000x reference)
//
#include <hip/hip_runtime.h>
#include <math.h>

#define EPS 1e-7f
#define NETS 3
#define ROWP 656                  // rows per net (650 useful: 640 outer + 10 bias)
#define NROW_TOT (NETS*ROWP)      // 1968 floats between j's in sU
#define G4 164                    // ROWP/4 groups per net
#define GPW 41                    // groups per wave per net (4 waves x 41 = 164)
#define PERNET4 (G4*64)           // 10496 float4s per net
#define W2R_F4_TOT (NETS*PERNET4) // 31488 float4s

// ---------------------------------------------------------------------------
// K1: head-reduced hyper-weights packed [net][g][hid][4rows], row ordering
// row' = kk*64 + h (kk-major) for rows < 640; rows 640..649 = b2 path
// (kk = row-640); rows 650..655 zero pad.
// col(kk) = kk*256 for kk<9, 2304 for kk==9 (the "+b" einsum term, f'[9]=1).
// ---------------------------------------------------------------------------
__global__ __launch_bounds__(256) void prep_w2r(
    const float* __restrict__ W2A, const float* __restrict__ b2A,
    const float* __restrict__ W2E, const float* __restrict__ b2E,
    const float* __restrict__ W2L, const float* __restrict__ b2L,
    const float* __restrict__ merger, float* __restrict__ W2r)
{
    int idx = blockIdx.x * 256 + threadIdx.x;      // one float4 per thread
    if (idx >= W2R_F4_TOT) return;
    int net = idx / PERNET4;
    int rem = idx - net * PERNET4;
    int g4  = rem >> 6;
    int hid = rem & 63;

    float m0 = merger[hid], m1 = merger[64+hid], m2 = merger[128+hid], m3 = merger[192+hid];
    float mx = fmaxf(fmaxf(m0, m1), fmaxf(m2, m3));
    float e0 = expf(m0-mx), e1 = expf(m1-mx), e2 = expf(m2-mx), e3 = expf(m3-mx);
    float inv = 1.0f / (e0+e1+e2+e3);
    float w0 = e0*inv, w1 = e1*inv, w2 = e2*inv, w3 = e3*inv;

    const float* W2 = (net==0) ? W2A : ((net==1) ? W2E : W2L);
    const float* b2 = (net==0) ? b2A : ((net==1) ? b2E : b2L);

    float4 v;
    float* vp = &v.x;
    #pragma unroll
    for (int r = 0; r < 4; ++r) {
        int row = g4*4 + r;
        float val = 0.0f;
        if (row < 650) {
            const float* src;
            int kk;
            if (row < 640) { kk = row >> 6; int h = row & 63; src = W2 + h*2560; }
            else           { kk = row - 640;                  src = b2; }
            int col = (kk < 9) ? kk*256 : 2304;
            val = w0*src[col+hid] + w1*src[col+64+hid] + w2*src[col+128+hid] + w3*src[col+192+hid];
        }
        vp[r] = val;
    }
    ((float4*)W2r)[idx] = v;
}

// ---------------------------------------------------------------------------
// K2: ONE block per agent (384 x 256), all 384 co-resident (63 KB LDS ->
// 2 blocks/CU capacity). Register/shuffle front-end, full U build, W2r read
// once per block (rows split across waves, 1-deep prefetch), inline epilogue.
// Zero cross-block communication. NOTE: all __shfl stay at full-exec scope
// (divergent-branch shfl from an inactive source lane is undefined -- the
// R8/R9 bug).
// ---------------------------------------------------------------------------
__global__ __launch_bounds__(256, 2) void agent_kernel(
    const float* __restrict__ inputs, const float* __restrict__ actions,
    const float* __restrict__ W1A, const float* __restrict__ b1A,
    const float* __restrict__ W1E, const float* __restrict__ b1E,
    const float* __restrict__ W1L, const float* __restrict__ b1L,
    const float* __restrict__ W2r,
    const float* __restrict__ fc1w, const float* __restrict__ fc1b,
    const float* __restrict__ fc2w, const float* __restrict__ fc2b,
    float* __restrict__ out_q, float* __restrict__ out_x)
{
    __shared__ __align__(16) float sU[8 * NROW_TOT];   // 62,976 B; reused for sZp/sZ
    __shared__ float sSt[8], sCt[8], sAct[3];
    __shared__ float sRed[4];

    const int tid   = threadIdx.x;
    const int agent = blockIdx.x;
    const int lane  = tid & 63;
    const int w     = tid >> 6;
    const int q     = lane >> 4, hh = lane & 15;

    // ---- W1 columns for h = lane (global, coalesced, once) ----
    float w1r[3][9], b1r[3];
    {
        const float* Ws[3] = {W1A, W1E, W1L};
        const float* bs[3] = {b1A, b1E, b1L};
        #pragma unroll
        for (int net = 0; net < 3; ++net) {
            #pragma unroll
            for (int kk = 0; kk < 9; ++kk) w1r[net][kk] = Ws[net][kk*64 + lane];
            b1r[net] = bs[net][lane];
        }
    }

    // ---- issue W2r preload for iteration 0 (overlaps the whole front-end) ----
    const float4* Wp = (const float4*)W2r;
    const int base = w * GPW;
    float4 wk0, wk1, wk2, wk3;
    {
        int g = base + q;
        const float4* wb = Wp + g*64 + hh;
        wk0 = wb[0]; wk1 = wb[16]; wk2 = wb[32]; wk3 = wb[48];
    }

    // ---- obs gather: one float per lane, distribute via shuffles ----
    float ob = 0.0f;
    if (lane < 30)      ob = inputs[agent*30 + lane];
    else if (lane < 32) ob = actions[agent*2 + (lane - 30)];

    // ---- per-entity geometry, entity e = lane&7 (redundant x8 per wave) ----
    int e = lane & 7;
    int ppos, vpos; bool lmk = false;
    if (e < 2)      { ppos = 10+2*e;     vpos = 20+2*e; }
    else if (e < 5) { ppos = 14+2*(e-2); vpos = 24+2*(e-2); }
    else            { ppos = 4+2*(e-5);  vpos = 0; lmk = true; }
    float px = __shfl(ob, ppos), py = __shfl(ob, ppos+1);
    float vx = __shfl(ob, vpos), vy = __shfl(ob, vpos+1);
    if (lmk) { vx = -vx; vy = -vy; }
    float d  = sqrtf(px*px + py*py);
    float st = py / (d + EPS), ct = px / (d + EPS);
    float vn = sqrtf(vx*vx + vy*vy);
    float sa = vy / (vn + EPS), ca = vx / (vn + EPS);
    float rb0 = expf(-0.02f * d * d);
    float d5  = d - 5.0f,  rb1 = expf(-0.02f * d5 * d5);
    float d10 = d - 10.0f, rb2 = expf(-0.02f * d10 * d10);

    // stash geometry/action for the inline epilogue.
    // Shuffles hoisted to FULL-EXEC scope; only the stores are predicated.
    if (w == 0 && lane < 8) { sSt[lane] = st; sCt[lane] = ct; }
    float ax = __shfl(ob, 30), ay = __shfl(ob, 31);
    if (tid == 0) {
        float an = sqrtf(ax*ax + ay*ay);
        sAct[0] = an; sAct[1] = ay/(an+EPS); sAct[2] = ax/(an+EPS);
    }

    // ---- pair features, pair p = lane (k = lane&7, j = lane>>3) ----
    int jj = lane >> 3;
    float st_j = __shfl(st, jj), ct_j = __shfl(ct, jj);
    float vx_j = __shfl(vx, jj), vy_j = __shfl(vy, jj);
    float f0 = rb0, f1 = rb1, f2 = rb2;
    float f3 = st*ct_j - ct*st_j;
    float f4 = ct*ct_j + st*st_j;
    float f5 = sa*ct_j - ca*st_j;
    float f6 = ca*ct_j + sa*st_j;
    float f7 = vx - vx_j;
    float f8 = vy - vy_j;

    // ---- U build: wave w handles j = 2w, 2w+1; lane = h; ALL 10 kk ----
    #pragma unroll
    for (int t = 0; t < 2; ++t) {
        int j = 2*w + t;
        #pragma unroll
        for (int net = 0; net < NETS; ++net) {
            int ks = (net==0) ? 0 : ((net==1) ? 2 : 5);
            int kn = (net==0) ? 2 : 3;
            float v0=0.f,v1=0.f,v2=0.f,v3=0.f,v4=0.f,v5=0.f,v6=0.f,v7=0.f,v8=0.f,v9=0.f;
            float g0s=0.f,g1s=0.f,g2s=0.f,g3s=0.f,g4s=0.f,g5s=0.f,g6s=0.f,g7s=0.f,g8s=0.f;
            for (int qq = 0; qq < kn; ++qq) {
                int p = j*8 + ks + qq;                 // wave-uniform broadcast
                float s0=__shfl(f0,p), s1=__shfl(f1,p), s2=__shfl(f2,p);
                float s3=__shfl(f3,p), s4=__shfl(f4,p), s5=__shfl(f5,p);
                float s6=__shfl(f6,p), s7=__shfl(f7,p), s8=__shfl(f8,p);
                float acc = b1r[net];
                acc = fmaf(s0, w1r[net][0], acc);
                acc = fmaf(s1, w1r[net][1], acc);
                acc = fmaf(s2, w1r[net][2], acc);
                acc = fmaf(s3, w1r[net][3], acc);
                acc = fmaf(s4, w1r[net][4], acc);
                acc = fmaf(s5, w1r[net][5], acc);
                acc = fmaf(s6, w1r[net][6], acc);
                acc = fmaf(s7, w1r[net][7], acc);
                acc = fmaf(s8, w1r[net][8], acc);
                float H = (acc > 0.0f) ? acc : 0.01f*acc;
                v0 = fmaf(H, s0, v0);  g0s += s0;
                v1 = fmaf(H, s1, v1);  g1s += s1;
                v2 = fmaf(H, s2, v2);  g2s += s2;
                v3 = fmaf(H, s3, v3);  g3s += s3;
                v4 = fmaf(H, s4, v4);  g4s += s4;
                v5 = fmaf(H, s5, v5);  g5s += s5;
                v6 = fmaf(H, s6, v6);  g6s += s6;
                v7 = fmaf(H, s7, v7);  g7s += s7;
                v8 = fmaf(H, s8, v8);  g8s += s8;
                v9 += H;                               // f'[9] = 1
            }
            float* dst = sU + (j*NETS + net)*ROWP + lane;
            dst[0]     = v0;
            dst[64]    = v1;
            dst[128]   = v2;
            dst[192]   = v3;
            dst[256]   = v4;
            dst[320]   = v5;
            dst[384]   = v6;
            dst[448]   = v7;
            dst[512]   = v8;
            dst[576]   = v9;
            // rows 640..649 bias (lane<10) + 650..655 pad (lanes 10..15)
            if (lane < 16) {
                float bv = 0.0f;
                bv = (lane==0) ? g0s : bv;
                bv = (lane==1) ? g1s : bv;
                bv = (lane==2) ? g2s : bv;
                bv = (lane==3) ? g3s : bv;
                bv = (lane==4) ? g4s : bv;
                bv = (lane==5) ? g5s : bv;
                bv = (lane==6) ? g6s : bv;
                bv = (lane==7) ? g7s : bv;
                bv = (lane==8) ? g8s : bv;
                bv = (lane==9) ? (float)kn : bv;       // sum of f'[9]=1 over kn pairs
                sU[(j*NETS + net)*ROWP + 640 + lane] = bv;
            }
        }
    }
    __syncthreads();                                   // barrier 1

    // ---- contraction: rows split across waves; 1-deep global prefetch.
    //      it = net*11 + u; u<10 full (offset u*4+q), u==10 tail (offset 40,
    //      q==0 lanes only FMA). ----
    float acc[8][4];
    #pragma unroll
    for (int j = 0; j < 8; ++j)
        #pragma unroll
        for (int k = 0; k < 4; ++k) acc[j][k] = 0.0f;

    for (int it = 0; it < 33; ++it) {
        int net = it / 11, u = it - net*11;
        int g = base + ((u == 10) ? 40 : u*4 + q);
        float4 nk0, nk1, nk2, nk3;
        if (it < 32) {
            int nit = it + 1;
            int nnet = nit / 11, nu = nit - nnet*11;
            int ng = base + ((nu == 10) ? 40 : nu*4 + q);
            const float4* wb = Wp + (nnet*G4 + ng)*64 + hh;
            nk0 = wb[0]; nk1 = wb[16]; nk2 = wb[32]; nk3 = wb[48];
        }
        if (u != 10 || q == 0) {
            const float* Ub = sU + net*ROWP + g*4;
            #pragma unroll
            for (int j = 0; j < 8; ++j) {
                float4 uu = *(const float4*)(Ub + j*NROW_TOT);
                acc[j][0] = fmaf(uu.x,wk0.x, fmaf(uu.y,wk0.y, fmaf(uu.z,wk0.z, fmaf(uu.w,wk0.w, acc[j][0]))));
                acc[j][1] = fmaf(uu.x,wk1.x, fmaf(uu.y,wk1.y, fmaf(uu.z,wk1.z, fmaf(uu.w,wk1.w, acc[j][1]))));
                acc[j][2] = fmaf(uu.x,wk2.x, fmaf(uu.y,wk2.y, fmaf(uu.z,wk2.z, fmaf(uu.w,wk2.w, acc[j][2]))));
                acc[j][3] = fmaf(uu.x,wk3.x, fmaf(uu.y,wk3.y, fmaf(uu.z,wk3.z, fmaf(uu.w,wk3.w, acc[j][3]))));
            }
        }
        wk0 = nk0; wk1 = nk1; wk2 = nk2; wk3 = nk3;
    }

    // ---- q-reduce (butterfly, full exec); q==0 lanes hold wave totals ----
    float vr[8][4];
    #pragma unroll
    for (int j = 0; j < 8; ++j)
        #pragma unroll
        for (int k = 0; k < 4; ++k) {
            float v = acc[j][k];
            v += __shfl_xor(v, 16);
            v += __shfl_xor(v, 32);
            vr[j][k] = v;
        }
    __syncthreads();                                   // barrier 2 (sU reads done)
    {                                                  // sZp aliases sU[0..2047]
        float* sZp = sU;
        if (q == 0) {
            #pragma unroll
            for (int j = 0; j < 8; ++j)
                #pragma unroll
                for (int k = 0; k < 4; ++k)
                    sZp[(w*8 + j)*64 + k*16 + hh] = vr[j][k];
        }
    }
    __syncthreads();                                   // barrier 3
    float* sZ = sU + 2048;                             // 512 floats
    for (int o = tid; o < 512; o += 256) {
        float z = sU[o] + sU[512+o] + sU[1024+o] + sU[1536+o];
        sZ[o] = (z > 0.0f) ? z : 0.0f;                 // relu folded in
    }
    __syncthreads();                                   // barrier 4

    // ---- inline epilogue: x = relu([reluZ, an, act_angle]@fc1+b); q=mean ----
    {
        float an  = sAct[0], sb = sAct[1], cb = sAct[2];
        float anr = (an > 0.0f) ? an : 0.0f;
        float myq = 0.0f;
        #pragma unroll
        for (int i = 0; i < 2; ++i) {
            int o = i*256 + tid;
            int j = o >> 6, c = o & 63;
            float a1 = fc1b[c];
            #pragma unroll 8
            for (int dd = 0; dd < 64; ++dd)
                a1 = fmaf(sZ[j*64 + dd], fc1w[dd*64 + c], a1);
            float aa0 = sb*sCt[j] - cb*sSt[j];
            float aa1 = cb*sCt[j] + sb*sSt[j];
            aa0 = (aa0 > 0.0f) ? aa0 : 0.0f;
            aa1 = (aa1 > 0.0f) ? aa1 : 0.0f;
            a1 = fmaf(anr, fc1w[64*64 + c], a1);
            a1 = fmaf(aa0, fc1w[65*64 + c], a1);
            a1 = fmaf(aa1, fc1w[66*64 + c], a1);
            float x1 = (a1 > 0.0f) ? a1 : 0.0f;
            out_x[(agent*8 + j)*64 + c] = x1;
            myq = fmaf(x1, fc2w[c], myq);
        }
        for (int off = 32; off; off >>= 1) myq += __shfl_down(myq, off);
        if (lane == 0) sRed[w] = myq;
        __syncthreads();
        if (tid == 0) out_q[agent] = (sRed[0] + sRed[1] + sRed[2] + sRed[3]) * 0.125f + fc2b[0];
    }
}

extern "C" void kernel_launch(void* const* d_in, const int* in_sizes, int n_in,
                              void* d_out, int out_size, void* d_ws, size_t ws_size,
                              hipStream_t stream) {
    const float* inputs  = (const float*)d_in[0];
    const float* actions = (const float*)d_in[2];
    const float* hA1_w = (const float*)d_in[3];  const float* hA1_b = (const float*)d_in[4];
    const float* hA2_w = (const float*)d_in[5];  const float* hA2_b = (const float*)d_in[6];
    const float* hE1_w = (const float*)d_in[7];  const float* hE1_b = (const float*)d_in[8];
    const float* hE2_w = (const float*)d_in[9];  const float* hE2_b = (const float*)d_in[10];
    const float* hL1_w = (const float*)d_in[11]; const float* hL1_b = (const float*)d_in[12];
    const float* hL2_w = (const float*)d_in[13]; const float* hL2_b = (const float*)d_in[14];
    const float* merger = (const float*)d_in[15];
    const float* fc1w = (const float*)d_in[16];  const float* fc1b = (const float*)d_in[17];
    const float* fc2w = (const float*)d_in[18];  const float* fc2b = (const float*)d_in[19];

    float* W2r = (float*)d_ws;              // 31488 float4 = 503,808 B
    float* q   = (float*)d_out;
    float* x   = q + 384;

    prep_w2r<<<(W2R_F4_TOT + 255)/256, 256, 0, stream>>>(
        hA2_w, hA2_b, hE2_w, hE2_b, hL2_w, hL2_b, merger, W2r);
    agent_kernel<<<384, 256, 0, stream>>>(
        inputs, actions, hA1_w, hA1_b, hE1_w, hE1_b, hL1_w, hL1_b,
        W2r, fc1w, fc1b, fc2w, fc2b, q, x);
}